// Round 4
// baseline (34.533 us; speedup 1.0000x reference)
//
#include <hip/hip_runtime.h>

// out[f] = sum_n w[n] * (2/sqrt(pi)) * c[n]^2 * arg * exp(-arg^2),
//   arg = (B_mean[n] - B_val[f]) * c[n], masked to |arg| <= 2.5.
//
// Refactor: d = B_mean - B_val;  contrib = s3 * d * exp2(-cl * d^2)
//   s3 = (2/sqrt(pi)) * w * c^3,  cl = c^2 * log2(e)
// mask: |arg| <= 2.5  <=>  u = cl*d^2 <= 6.25*log2(e)
//
// Round-4 structure (post-mortem of r1-r3: time scales as 1/resident-waves,
// VALUBusy 16% -> latency-bound on the LDS broadcast chain, NOT atomics):
//   stage 0: precompute per-line float4 {bm, cl, s3, 0} table in ws.
//   stage 1: NO LDS, NO barrier. Per-line constants read via loop-uniform
//            index from const __restrict__ pointer -> scalar s_load into
//            SGPRs (folded as SGPR operands into the VALU ops). CHUNK=32
//            lines/block, 2048 blocks -> 8 waves/SIMD for latency hiding.
//   stage 2: column-sum the 2048 partial spectra (plain stores, no atomics).

namespace {
constexpr float K_2_SQRT_PI = 1.1283791670955126f;  // 2/sqrt(pi)
constexpr float LOG2E       = 1.4426950408889634f;
constexpr float CUT_U       = 6.25f * 1.4426950408889634f;  // (2.5^2)*log2e
constexpr int BLOCK = 256;   // threads per stage-1 block
constexpr int FPT   = 4;     // fields per thread
constexpr int NF    = BLOCK * FPT;  // fields per block-column (1024)
constexpr int CHUNK = 32;    // lines per stage-1 block
}

// ---------------- Stage 0: per-line constant table ----------------
__global__ __launch_bounds__(256) void prep_kernel(
    const float* __restrict__ B_mean,
    const float* __restrict__ c_ext,
    const float* __restrict__ weights,
    float4* __restrict__ lconst,
    int n_lines, int n_pad)
{
    const int i = blockIdx.x * 256 + threadIdx.x;
    if (i < n_pad) {
        float bm = 0.0f, cc = 0.0f, ww = 0.0f;
        if (i < n_lines) { bm = B_mean[i]; cc = c_ext[i]; ww = weights[i]; }
        const float c2 = cc * cc;
        // padded lines get s3=0 -> contribute exactly 0
        lconst[i] = make_float4(bm, c2 * LOG2E, K_2_SQRT_PI * ww * c2 * cc, 0.0f);
    }
}

// ---------------- Stage 1: partial spectra, scalar-broadcast lines --------
__global__ __launch_bounds__(BLOCK, 8) void spectra_partial_kernel(
    const float4* __restrict__ lconst,   // [n_chunks*CHUNK]
    const float* __restrict__ B_val,
    float* __restrict__ part,            // [n_chunks][nft*NF]
    int n_fields, int nft)
{
    const int tid = threadIdx.x;
    const int ft  = blockIdx.y;                 // field tile
    const int f0g = ft * NF + tid * FPT;        // global field index
    float bv0 = 0.0f, bv1 = 0.0f, bv2 = 0.0f, bv3 = 0.0f;
    if (f0g + FPT <= n_fields) {
        const float4 v = *reinterpret_cast<const float4*>(&B_val[f0g]);
        bv0 = v.x; bv1 = v.y; bv2 = v.z; bv3 = v.w;
    } else {
        if (f0g + 0 < n_fields) bv0 = B_val[f0g + 0];
        if (f0g + 1 < n_fields) bv1 = B_val[f0g + 1];
        if (f0g + 2 < n_fields) bv2 = B_val[f0g + 2];
        if (f0g + 3 < n_fields) bv3 = B_val[f0g + 3];
    }

    // Uniform-index loads from const __restrict__ -> s_load (SGPR broadcast).
    const float4* __restrict__ Lp = lconst + blockIdx.x * CHUNK;

    float acc0 = 0.0f, acc1 = 0.0f, acc2 = 0.0f, acc3 = 0.0f;
#pragma unroll
    for (int i = 0; i < CHUNK; ++i) {
        const float4 L = Lp[i];

        float d, u, e, t;
        d = L.x - bv0; u = (L.y * d) * d; e = __builtin_amdgcn_exp2f(-u);
        t = L.z * d;   e = (u <= CUT_U) ? e : 0.0f; acc0 = fmaf(t, e, acc0);

        d = L.x - bv1; u = (L.y * d) * d; e = __builtin_amdgcn_exp2f(-u);
        t = L.z * d;   e = (u <= CUT_U) ? e : 0.0f; acc1 = fmaf(t, e, acc1);

        d = L.x - bv2; u = (L.y * d) * d; e = __builtin_amdgcn_exp2f(-u);
        t = L.z * d;   e = (u <= CUT_U) ? e : 0.0f; acc2 = fmaf(t, e, acc2);

        d = L.x - bv3; u = (L.y * d) * d; e = __builtin_amdgcn_exp2f(-u);
        t = L.z * d;   e = (u <= CUT_U) ? e : 0.0f; acc3 = fmaf(t, e, acc3);
    }

    // Coalesced float4 store of this block's partial spectrum.
    const long long row = (long long)blockIdx.x * (nft * NF);
    reinterpret_cast<float4*>(&part[row + ft * NF])[tid] =
        make_float4(acc0, acc1, acc2, acc3);
}

// ---------------- Stage 2: column-sum partials -> out ----------------
__global__ __launch_bounds__(256) void spectra_reduce_kernel(
    const float* __restrict__ part, float* __restrict__ out,
    int n_chunks, int n_fields, int nft)
{
    __shared__ float red[32][8];
    const int t  = threadIdx.x;
    const int fl = t & 7;        // field within block's 8-field group
    const int s  = t >> 3;       // partial-slice 0..31
    const int f  = blockIdx.x * 8 + fl;
    const int rowlen = nft * NF;

    float acc = 0.0f;
    if (f < rowlen) {
#pragma unroll 8
        for (int p = s; p < n_chunks; p += 32)
            acc += part[(long long)p * rowlen + f];
    }
    red[s][fl] = acc;
    __syncthreads();

    if (s == 0 && f < n_fields) {
        float a = 0.0f;
#pragma unroll
        for (int k = 0; k < 32; ++k) a += red[k][fl];
        out[f] = a;  // plain store overwrites harness poison
    }
}

// ---------------- Fallback (tiny ws): atomic path ----------------
__global__ void zero_out_kernel(float* __restrict__ out, int n) {
    int i = blockIdx.x * blockDim.x + threadIdx.x;
    if (i < n) out[i] = 0.0f;
}

__global__ __launch_bounds__(1024) void spectra_atomic_kernel(
    const float* __restrict__ B_mean,
    const float* __restrict__ c_ext,
    const float* __restrict__ B_val,
    const float* __restrict__ weights,
    float* __restrict__ out,
    int n_lines, int n_fields)
{
    __shared__ float4 lds[256];
    const int tid  = threadIdx.x;
    const int base = blockIdx.x * 256;
    if (tid < 256) {
        const int n = base + tid;
        float bm = 0.0f, cc = 0.0f, ww = 0.0f;
        if (n < n_lines) { bm = B_mean[n]; cc = c_ext[n]; ww = weights[n]; }
        const float c2 = cc * cc;
        lds[tid] = make_float4(bm, c2 * LOG2E, K_2_SQRT_PI * ww * c2 * cc, 0.0f);
    }
    __syncthreads();
    const int f = tid;
    const float bv = (f < n_fields) ? B_val[f] : 0.0f;
    const int nl = min(256, n_lines - base);
    float acc = 0.0f;
#pragma unroll 4
    for (int i = 0; i < nl; ++i) {
        const float4 L = lds[i];
        const float d = L.x - bv;
        const float u = (L.y * d) * d;
        const float e = __builtin_amdgcn_exp2f(-u);
        acc += (L.z * d) * ((u <= CUT_U) ? e : 0.0f);
    }
    if (f < n_fields) atomicAdd(&out[f], acc);
}

extern "C" void kernel_launch(void* const* d_in, const int* in_sizes, int n_in,
                              void* d_out, int out_size, void* d_ws, size_t ws_size,
                              hipStream_t stream) {
    const float* B_mean  = (const float*)d_in[0];
    const float* c_ext   = (const float*)d_in[1];
    const float* B_val   = (const float*)d_in[2];
    const float* weights = (const float*)d_in[3];
    float* out = (float*)d_out;

    const int n_lines  = in_sizes[0];
    const int n_fields = in_sizes[2];

    const int n_chunks = (n_lines + CHUNK - 1) / CHUNK;
    const int n_pad    = n_chunks * CHUNK;
    const int nft      = (n_fields + NF - 1) / NF;  // field tiles (1 here)

    const size_t lconst_bytes = (size_t)n_pad * sizeof(float4);
    const size_t part_bytes   = (size_t)n_chunks * nft * NF * sizeof(float);

    if (lconst_bytes + part_bytes > ws_size) {
        // Workspace too small: atomic fallback.
        zero_out_kernel<<<(out_size + 255) / 256, 256, 0, stream>>>(out, out_size);
        spectra_atomic_kernel<<<(n_lines + 255) / 256, 1024, 0, stream>>>(
            B_mean, c_ext, B_val, weights, out, n_lines, n_fields);
        return;
    }

    float4* lconst = (float4*)d_ws;
    float*  part   = (float*)((char*)d_ws + lconst_bytes);

    prep_kernel<<<(n_pad + 255) / 256, 256, 0, stream>>>(
        B_mean, c_ext, weights, lconst, n_lines, n_pad);

    dim3 grid1(n_chunks, nft);
    spectra_partial_kernel<<<grid1, BLOCK, 0, stream>>>(
        lconst, B_val, part, n_fields, nft);

    spectra_reduce_kernel<<<(nft * NF + 7) / 8, 256, 0, stream>>>(
        part, out, n_chunks, n_fields, nft);
}